// Round 8
// baseline (227.050 us; speedup 1.0000x reference)
//
#include <hip/hip_runtime.h>
#include <stdint.h>

// GCN 2-layer: out = drop(relu(A_hat * (drop(relu((A_hat*X)*W1+b1)) * W2) + b2))
// - A_hat applied at 256 ch both layers (aggregate-first / multiply-first)
// - CSR gather aggregation; entry = int2{src, dinv[src]} (2-deep chain, no waste)
// - Gather: 1 wave/node, unroll-8 main + scalar tail (round-5 proven shape)
// - GEMMs: bf16x3 split MFMA, 128x128 tiles, global_load_lds width-16 staging
// - Dropout: JAX threefry2x32, partitionable mode
// - 8 dispatches

#define C_IN 256
#define C_HID 512
#define C_OUT 256

typedef unsigned short ushort_t;
typedef __bf16 bf16x8 __attribute__((ext_vector_type(8)));
typedef float floatx4 __attribute__((ext_vector_type(4)));

// async global->LDS, 16B per lane; LDS dest = wave-uniform base + lane*16
__device__ __forceinline__ void gload_lds16(const void* g, void* l) {
  __builtin_amdgcn_global_load_lds(
      (const __attribute__((address_space(1))) unsigned*)g,
      (__attribute__((address_space(3))) unsigned*)l, 16, 0, 0);
}

// ---------------- Threefry-2x32 (matches JAX) ----------------
__host__ __device__ __forceinline__ void tf_rounds(unsigned& x0, unsigned& x1,
                                                   unsigned k0, unsigned k1) {
  unsigned k2 = k0 ^ k1 ^ 0x1BD11BDAu;
#define ROT(r) { x0 += x1; x1 = (x1 << r) | (x1 >> (32 - r)); x1 ^= x0; }
  x0 += k0; x1 += k1;
  ROT(13) ROT(15) ROT(26) ROT(6)
  x0 += k1; x1 += k2 + 1u;
  ROT(17) ROT(29) ROT(16) ROT(24)
  x0 += k2; x1 += k0 + 2u;
  ROT(13) ROT(15) ROT(26) ROT(6)
  x0 += k0; x1 += k1 + 3u;
  ROT(17) ROT(29) ROT(16) ROT(24)
  x0 += k1; x1 += k2 + 4u;
  ROT(13) ROT(15) ROT(26) ROT(6)
  x0 += k2; x1 += k0 + 5u;
#undef ROT
}

__device__ __forceinline__ float drop_scale(unsigned j, unsigned k0, unsigned k1) {
  unsigned x0 = 0u, x1 = j;
  tf_rounds(x0, x1, k0, k1);
  unsigned bits = x0 ^ x1;
  float u = __uint_as_float((bits >> 9) | 0x3f800000u) - 1.0f;
  return (u < 0.5f) ? 2.0f : 0.0f;
}

// bf16 helpers (RNE)
__device__ __forceinline__ ushort_t f2bf(float f) {
  unsigned u = __float_as_uint(f);
  unsigned r = (u + 0x7fffu + ((u >> 16) & 1u)) >> 16;
  return (ushort_t)r;
}
__device__ __forceinline__ float bf2f(ushort_t h) {
  return __uint_as_float(((unsigned)h) << 16);
}

// ---------------- setup: blocks 0..NB-1 zero cnt; block NB detects dtype ----
__global__ __launch_bounds__(256) void k_setup(const unsigned* __restrict__ raw,
                                               unsigned* flag, int nwords,
                                               int* __restrict__ cnt, int n,
                                               int nb) {
  if ((int)blockIdx.x < nb) {
    int i = blockIdx.x * 256 + threadIdx.x;
    if (i < n) cnt[i] = 0;
    return;
  }
  __shared__ unsigned sh[256];
  unsigned acc = 0;
  for (int i = 1 + 2 * (int)threadIdx.x; i < nwords; i += 512) acc |= raw[i];
  sh[threadIdx.x] = acc;
  __syncthreads();
  for (int s = 128; s > 0; s >>= 1) {
    if ((int)threadIdx.x < s) sh[threadIdx.x] |= sh[threadIdx.x + s];
    __syncthreads();
  }
  if (threadIdx.x == 0) *flag = (sh[0] == 0u) ? 1u : 0u;  // 1 => int64
}

// convert + fused dst-degree histogram (cnt pre-zeroed)
__global__ __launch_bounds__(256) void k_convert(const void* __restrict__ raw,
                                                 const unsigned* __restrict__ flag,
                                                 int* __restrict__ eic,
                                                 int* __restrict__ cnt,
                                                 int E) {
  int i = blockIdx.x * 256 + threadIdx.x;
  if (i >= 2 * E) return;
  int v;
  if (*flag) v = (int)((const long long*)raw)[i];
  else       v = ((const int*)raw)[i];
  eic[i] = v;
  if (i >= E) atomicAdd(&cnt[v], 1);  // dst half -> in-degree
}

// ---------------- single-block scan (1024 thr x 16 elem) + dinv + cursor ----
#define SCAN_CH 16
__global__ __launch_bounds__(1024) void k_scan1(const int* __restrict__ cnt,
                                                int* __restrict__ roff,
                                                int* __restrict__ cursor,
                                                float* __restrict__ dinv, int n) {
  __shared__ int sh[1024];
  const int t = threadIdx.x;
  const int base = t * SCAN_CH;
  int vv[SCAN_CH], loc[SCAN_CH];
  int sum = 0;
#pragma unroll
  for (int i = 0; i < SCAN_CH; ++i) {
    int idx = base + i;
    int v = (idx < n) ? cnt[idx] : 0;
    vv[i] = v;
    loc[i] = sum;
    sum += v;
  }
  sh[t] = sum;
  __syncthreads();
  for (int s = 1; s < 1024; s <<= 1) {
    int v = (t >= s) ? sh[t - s] : 0;
    __syncthreads();
    sh[t] += v;
    __syncthreads();
  }
  int tex = sh[t] - sum;
#pragma unroll
  for (int i = 0; i < SCAN_CH; ++i) {
    int idx = base + i;
    if (idx < n) {
      int excl = tex + loc[i];
      roff[idx] = excl;
      cursor[idx] = excl;
      dinv[idx] = rsqrtf((float)(vv[i] + 1));  // +1 self-loop
    }
  }
  if (t == 1023) roff[n] = sh[1023];
}

// ---------------- fused scatter (blocks < SB) + weight convert/transpose ----
__global__ __launch_bounds__(256) void k_scat_wconv(
    const int* __restrict__ eic, int* __restrict__ cursor,
    const float* __restrict__ dinv, int2* __restrict__ csrw, int E, int SB,
    const float* __restrict__ W1, const float* __restrict__ W2,
    ushort_t* __restrict__ h1, ushort_t* __restrict__ l1,
    ushort_t* __restrict__ h2, ushort_t* __restrict__ l2) {
  int b = blockIdx.x;
  if (b < SB) {
    int e = b * 256 + threadIdx.x;
    if (e >= E) return;
    int s = eic[e], d = eic[E + e];
    int slot = atomicAdd(&cursor[d], 1);
    int2 val;
    val.x = s;
    val.y = __float_as_int(dinv[s]);
    csrw[slot] = val;
    return;
  }
  int idx = (b - SB) * 256 + threadIdx.x;
  const int S1 = C_IN * C_HID;
  const int S2 = C_HID * C_OUT;
  if (idx >= S1 + S2) return;
  const float* W; ushort_t *hi, *lo; int K, Nn, li;
  if (idx < S1) { W = W1; hi = h1; lo = l1; K = C_IN; Nn = C_HID; li = idx; }
  else { W = W2; hi = h2; lo = l2; K = C_HID; Nn = C_OUT; li = idx - S1; }
  int k = li / Nn, n = li - k * Nn;
  float v = W[li];
  ushort_t h = f2bf(v);
  hi[(size_t)n * K + k] = h;
  lo[(size_t)n * K + k] = f2bf(v - bf2f(h));
}

// ---------------- gather: 4 nodes/block (1 wave each), unroll-8, no waste ---
template <int EPI>
__global__ __launch_bounds__(256) void k_gather4(const int* __restrict__ roff,
                                                 const int2* __restrict__ csrw,
                                                 const float* __restrict__ dinv,
                                                 const float* __restrict__ x,
                                                 const float* __restrict__ bias,
                                                 void* __restrict__ o1,
                                                 void* __restrict__ o2,
                                                 unsigned dk0, unsigned dk1) {
  const int g = threadIdx.x >> 6;
  const int lane = threadIdx.x & 63;
  const int node = blockIdx.x * 4 + g;
  float dd = dinv[node];
  float4 v = ((const float4*)(x + (size_t)node * 256))[lane];
  float4 acc = make_float4(dd * v.x, dd * v.y, dd * v.z, dd * v.w);
  int p = roff[node], end = roff[node + 1];
  for (; p + 8 <= end; p += 8) {
    int2 ew[8];
#pragma unroll
    for (int i = 0; i < 8; ++i) ew[i] = csrw[p + i];
#pragma unroll
    for (int i = 0; i < 8; ++i) {
      float w = __int_as_float(ew[i].y);
      float4 a = ((const float4*)(x + (size_t)ew[i].x * 256))[lane];
      acc.x += w * a.x; acc.y += w * a.y; acc.z += w * a.z; acc.w += w * a.w;
    }
  }
  for (; p < end; ++p) {
    int2 e = csrw[p];
    float w = __int_as_float(e.y);
    float4 a = ((const float4*)(x + (size_t)e.x * 256))[lane];
    acc.x += w * a.x; acc.y += w * a.y; acc.z += w * a.z; acc.w += w * a.w;
  }
  acc.x *= dd; acc.y *= dd; acc.z *= dd; acc.w *= dd;
  if (EPI) {
    float4 bb = ((const float4*)bias)[lane];
    acc.x = fmaxf(acc.x + bb.x, 0.0f);
    acc.y = fmaxf(acc.y + bb.y, 0.0f);
    acc.z = fmaxf(acc.z + bb.z, 0.0f);
    acc.w = fmaxf(acc.w + bb.w, 0.0f);
    unsigned jb = (unsigned)node * 256u + (unsigned)lane * 4u;
    acc.x *= drop_scale(jb + 0u, dk0, dk1);
    acc.y *= drop_scale(jb + 1u, dk0, dk1);
    acc.z *= drop_scale(jb + 2u, dk0, dk1);
    acc.w *= drop_scale(jb + 3u, dk0, dk1);
    ((float4*)o1)[(size_t)node * 64 + lane] = acc;
  } else {
    ushort_t h0 = f2bf(acc.x), h1 = f2bf(acc.y), h2 = f2bf(acc.z), h3 = f2bf(acc.w);
    ushort4 hv = make_ushort4(h0, h1, h2, h3);
    ushort4 lv = make_ushort4(f2bf(acc.x - bf2f(h0)), f2bf(acc.y - bf2f(h1)),
                              f2bf(acc.z - bf2f(h2)), f2bf(acc.w - bf2f(h3)));
    ((ushort4*)o1)[(size_t)node * 64 + lane] = hv;
    ((ushort4*)o2)[(size_t)node * 64 + lane] = lv;
  }
}

// ---------------- bf16x3 MFMA GEMM, global_load_lds staging ----------------
// Staging layout: thread t stages 16B at LDS byte offset t*16 (chunk 0) and
// 4096 + t*16 (chunk 1) => per wave: base (wave-uniform) + lane*16. Matches
// the global_load_lds wave-uniform-base + lane*size rule.
template <int EPI>
__global__ __launch_bounds__(256) void k_gemm3(
    const ushort_t* __restrict__ Ahi, const ushort_t* __restrict__ Alo,
    const ushort_t* __restrict__ Bhi, const ushort_t* __restrict__ Blo,
    const float* __restrict__ bias,
    ushort_t* __restrict__ Chi, ushort_t* __restrict__ Clo,  // EPI=1 outputs
    float* __restrict__ Cf,                                  // EPI=0 output
    int M, int N, int K, unsigned dk0, unsigned dk1) {
  __shared__ ushort_t sAh[128 * 32], sAl[128 * 32], sBh[128 * 32], sBl[128 * 32];
  const int t = threadIdx.x;
  const int lane = t & 63, wave = t >> 6;
  const int wm = wave & 1, wn = wave >> 1;
  const int quad = lane >> 4, l16 = lane & 15;
  const int row0 = blockIdx.y * 128, col0 = blockIdx.x * 128;
  const int srow = t >> 2;          // 0..63
  const int skc = (t & 3) * 8;      // k element offset (8 bf16 = 16B)
  const int wbase = wave * 512;     // wave-uniform LDS element base (1024 B)

  floatx4 acc[4][4] = {};

  const int ra0 = min(row0 + srow, M - 1);
  const int ra1 = min(row0 + 64 + srow, M - 1);
  const int rb0 = col0 + srow;
  const int rb1 = col0 + 64 + srow;

  for (int kt = 0; kt < K; kt += 32) {
    const size_t ka = (size_t)kt + skc;
    __syncthreads();  // prior iteration's LDS reads complete
    gload_lds16(Ahi + (size_t)ra0 * K + ka, &sAh[wbase]);
    gload_lds16(Ahi + (size_t)ra1 * K + ka, &sAh[2048 + wbase]);
    gload_lds16(Alo + (size_t)ra0 * K + ka, &sAl[wbase]);
    gload_lds16(Alo + (size_t)ra1 * K + ka, &sAl[2048 + wbase]);
    gload_lds16(Bhi + (size_t)rb0 * K + ka, &sBh[wbase]);
    gload_lds16(Bhi + (size_t)rb1 * K + ka, &sBh[2048 + wbase]);
    gload_lds16(Blo + (size_t)rb0 * K + ka, &sBl[wbase]);
    gload_lds16(Blo + (size_t)rb1 * K + ka, &sBl[2048 + wbase]);
    __syncthreads();  // drains vmcnt -> LDS valid

    bf16x8 ah[4], al[4], bh[4], bl[4];
#pragma unroll
    for (int i = 0; i < 4; ++i) {
      int off = (wm * 64 + i * 16 + l16) * 32 + quad * 8;
      ah[i] = *(const bf16x8*)&sAh[off];
      al[i] = *(const bf16x8*)&sAl[off];
    }
#pragma unroll
    for (int j = 0; j < 4; ++j) {
      int off = (wn * 64 + j * 16 + l16) * 32 + quad * 8;
      bh[j] = *(const bf16x8*)&sBh[off];
      bl[j] = *(const bf16x8*)&sBl[off];
    }
#pragma unroll
    for (int i = 0; i < 4; ++i)
#pragma unroll
      for (int j = 0; j < 4; ++j) {
        acc[i][j] = __builtin_amdgcn_mfma_f32_16x16x32_bf16(ah[i], bh[j], acc[i][j], 0, 0, 0);
        acc[i][j] = __builtin_amdgcn_mfma_f32_16x16x32_bf16(ah[i], bl[j], acc[i][j], 0, 0, 0);
        acc[i][j] = __builtin_amdgcn_mfma_f32_16x16x32_bf16(al[i], bh[j], acc[i][j], 0, 0, 0);
      }
  }

#pragma unroll
  for (int i = 0; i < 4; ++i) {
#pragma unroll
    for (int j = 0; j < 4; ++j) {
      int gc = col0 + wn * 64 + j * 16 + l16;
#pragma unroll
      for (int reg = 0; reg < 4; ++reg) {
        int gr = row0 + wm * 64 + i * 16 + quad * 4 + reg;
        if (gr >= M) continue;
        float v = acc[i][j][reg];
        size_t o = (size_t)gr * N + gc;
        if (EPI) {
          v += bias[gc];
          v = fmaxf(v, 0.0f);
          v *= drop_scale((unsigned)gr * (unsigned)N + (unsigned)gc, dk0, dk1);
          ushort_t h = f2bf(v);
          Chi[o] = h;
          Clo[o] = f2bf(v - bf2f(h));
        } else {
          Cf[o] = v;
        }
      }
    }
  }
}

extern "C" void kernel_launch(void* const* d_in, const int* in_sizes, int n_in,
                              void* d_out, int out_size, void* d_ws, size_t ws_size,
                              hipStream_t stream) {
  const float* x  = (const float*)d_in[0];
  const void*  ei = d_in[1];
  const float* W1 = (const float*)d_in[2];
  const float* b1 = (const float*)d_in[3];
  const float* W2 = (const float*)d_in[4];
  const float* b2 = (const float*)d_in[5];
  float* out = (float*)d_out;

  const int N = in_sizes[0] / C_IN;   // 10000
  const int E = in_sizes[1] / 2;      // 160000
  const int NB = (N + 255) / 256;     // 40

  // foldlike split(key(42)): dk_i = threefry((0,42), (0, i))
  unsigned a0 = 0u, a1 = 0u, b0 = 0u, b1k = 1u;
  tf_rounds(a0, a1, 0u, 42u);   // dk1
  tf_rounds(b0, b1k, 0u, 42u);  // dk2

  // workspace layout
  uintptr_t base = (uintptr_t)d_ws;
  unsigned*  flag   = (unsigned*)base;
  int*       cnt    = (int*)(base + 16 * 1024);               // 40 KB
  int*       roff   = (int*)(base + 64 * 1024);               // 40 KB (+1)
  int*       cursor = (int*)(base + 128 * 1024);              // 40 KB
  float*     dinv   = (float*)(base + 192 * 1024);            // 40 KB
  int*       eic    = (int*)(base + 256 * 1024);              // 1.28 MB
  int2*      csrw   = (int2*)(base + 2u * 1024 * 1024);       // 1.28 MB
  ushort_t*  Ahi    = (ushort_t*)(base + 4u  * 1024 * 1024);  // 5.12 MB
  ushort_t*  Alo    = (ushort_t*)(base + 10u * 1024 * 1024);  // 5.12 MB
  ushort_t*  H1hi   = (ushort_t*)(base + 16u * 1024 * 1024);  // 10.24 MB
  ushort_t*  H1lo   = (ushort_t*)(base + 27u * 1024 * 1024);  // 10.24 MB
  float*     hw2    = (float*)(base + 38u * 1024 * 1024);     // 10.24 MB
  ushort_t*  W1thi  = (ushort_t*)(base + 49u * 1024 * 1024);  // 256 KB
  ushort_t*  W1tlo  = (ushort_t*)(base + 49u * 1024 * 1024 + 512 * 1024);
  ushort_t*  W2thi  = (ushort_t*)(base + 50u * 1024 * 1024);
  ushort_t*  W2tlo  = (ushort_t*)(base + 50u * 1024 * 1024 + 512 * 1024);

  dim3 b256(256);
  const int SB = (E + 255) / 256;                             // 625 scatter blocks
  const int WB = (C_IN * C_HID + C_HID * C_OUT + 255) / 256;  // 1024 wconv blocks

  // 1: zero cnt + detect dtype
  k_setup<<<dim3(NB + 1), b256, 0, stream>>>((const unsigned*)ei, flag, 8192, cnt, N, NB);
  // 2: convert edges + degree histogram
  k_convert<<<dim3((2 * E + 255) / 256), b256, 0, stream>>>(ei, flag, eic, cnt, E);
  // 3: scan -> roff/cursor/dinv
  k_scan1<<<dim3(1), dim3(1024), 0, stream>>>(cnt, roff, cursor, dinv, N);
  // 4: scatter into weighted CSR + weight bf16-split transpose
  k_scat_wconv<<<dim3(SB + WB), b256, 0, stream>>>(eic, cursor, dinv, csrw, E, SB,
                                                   W1, W2, W1thi, W1tlo, W2thi, W2tlo);
  // 5: layer-1 aggregate -> bf16 split A
  k_gather4<0><<<dim3(N / 4), b256, 0, stream>>>(roff, csrw, dinv, x, nullptr,
                                                 Ahi, Alo, 0u, 0u);
  // 6: h1 = drop(relu(agg @ W1 + b1)) -> bf16 split
  k_gemm3<1><<<dim3(C_HID / 128, (N + 127) / 128), b256, 0, stream>>>(
      Ahi, Alo, W1thi, W1tlo, b1, H1hi, H1lo, nullptr, N, C_HID, C_IN, a0, a1);
  // 7: hw2 = h1 @ W2 (fp32 out)
  k_gemm3<0><<<dim3(C_OUT / 128, (N + 127) / 128), b256, 0, stream>>>(
      H1hi, H1lo, W2thi, W2tlo, nullptr, nullptr, nullptr, hw2, N, C_OUT, C_HID, 0u, 0u);
  // 8: out = drop(relu(A_hat * hw2 + b2))
  k_gather4<1><<<dim3(N / 4), b256, 0, stream>>>(roff, csrw, dinv, hw2, b2,
                                                 out, nullptr, b0, b1k);
}

// Round 9
// 220.787 us; speedup vs baseline: 1.0284x; 1.0284x over previous
//
#include <hip/hip_runtime.h>
#include <stdint.h>

// GCN 2-layer: out = drop(relu(A_hat * (drop(relu((A_hat*X)*W1+b1)) * W2) + b2))
// - A_hat applied at 256 ch both layers (aggregate-first / multiply-first)
// - CSR gather aggregation; entry = int2{src, dinv[src]} (2-deep chain, no waste)
// - Gather: 1 wave/node, unroll-8 main + scalar tail; layer-2 gathers bf16 rows
// - GEMMs: bf16x3 split MFMA, 128x128 tiles, VGPR-prefetch staging (round-5 proven)
// - GEMM2 outputs bf16 (halves write + final-gather traffic; error budget checked)
// - Dropout: JAX threefry2x32, partitionable mode
// - 8 dispatches

#define C_IN 256
#define C_HID 512
#define C_OUT 256

typedef unsigned short ushort_t;
typedef __bf16 bf16x8 __attribute__((ext_vector_type(8)));
typedef float floatx4 __attribute__((ext_vector_type(4)));

// ---------------- Threefry-2x32 (matches JAX) ----------------
__host__ __device__ __forceinline__ void tf_rounds(unsigned& x0, unsigned& x1,
                                                   unsigned k0, unsigned k1) {
  unsigned k2 = k0 ^ k1 ^ 0x1BD11BDAu;
#define ROT(r) { x0 += x1; x1 = (x1 << r) | (x1 >> (32 - r)); x1 ^= x0; }
  x0 += k0; x1 += k1;
  ROT(13) ROT(15) ROT(26) ROT(6)
  x0 += k1; x1 += k2 + 1u;
  ROT(17) ROT(29) ROT(16) ROT(24)
  x0 += k2; x1 += k0 + 2u;
  ROT(13) ROT(15) ROT(26) ROT(6)
  x0 += k0; x1 += k1 + 3u;
  ROT(17) ROT(29) ROT(16) ROT(24)
  x0 += k1; x1 += k2 + 4u;
  ROT(13) ROT(15) ROT(26) ROT(6)
  x0 += k2; x1 += k0 + 5u;
#undef ROT
}

__device__ __forceinline__ float drop_scale(unsigned j, unsigned k0, unsigned k1) {
  unsigned x0 = 0u, x1 = j;
  tf_rounds(x0, x1, k0, k1);
  unsigned bits = x0 ^ x1;
  float u = __uint_as_float((bits >> 9) | 0x3f800000u) - 1.0f;
  return (u < 0.5f) ? 2.0f : 0.0f;
}

// bf16 helpers (RNE)
__device__ __forceinline__ ushort_t f2bf(float f) {
  unsigned u = __float_as_uint(f);
  unsigned r = (u + 0x7fffu + ((u >> 16) & 1u)) >> 16;
  return (ushort_t)r;
}
__device__ __forceinline__ float bf2f(ushort_t h) {
  return __uint_as_float(((unsigned)h) << 16);
}

// row fragment readers (4 channels per lane)
__device__ __forceinline__ float4 row4(const float* x, int r, int lane) {
  return ((const float4*)(x + (size_t)r * 256))[lane];
}
__device__ __forceinline__ float4 row4(const ushort_t* x, int r, int lane) {
  ushort4 u = ((const ushort4*)(x + (size_t)r * 256))[lane];
  return make_float4(bf2f(u.x), bf2f(u.y), bf2f(u.z), bf2f(u.w));
}

// ---------------- setup: blocks 0..NB-1 zero cnt; block NB detects dtype ----
__global__ __launch_bounds__(256) void k_setup(const unsigned* __restrict__ raw,
                                               unsigned* flag, int nwords,
                                               int* __restrict__ cnt, int n,
                                               int nb) {
  if ((int)blockIdx.x < nb) {
    int i = blockIdx.x * 256 + threadIdx.x;
    if (i < n) cnt[i] = 0;
    return;
  }
  __shared__ unsigned sh[256];
  unsigned acc = 0;
  for (int i = 1 + 2 * (int)threadIdx.x; i < nwords; i += 512) acc |= raw[i];
  sh[threadIdx.x] = acc;
  __syncthreads();
  for (int s = 128; s > 0; s >>= 1) {
    if ((int)threadIdx.x < s) sh[threadIdx.x] |= sh[threadIdx.x + s];
    __syncthreads();
  }
  if (threadIdx.x == 0) *flag = (sh[0] == 0u) ? 1u : 0u;  // 1 => int64
}

// convert + fused dst-degree histogram (cnt pre-zeroed)
__global__ __launch_bounds__(256) void k_convert(const void* __restrict__ raw,
                                                 const unsigned* __restrict__ flag,
                                                 int* __restrict__ eic,
                                                 int* __restrict__ cnt,
                                                 int E) {
  int i = blockIdx.x * 256 + threadIdx.x;
  if (i >= 2 * E) return;
  int v;
  if (*flag) v = (int)((const long long*)raw)[i];
  else       v = ((const int*)raw)[i];
  eic[i] = v;
  if (i >= E) atomicAdd(&cnt[v], 1);  // dst half -> in-degree
}

// ---------------- single-block scan (1024 thr x 16 elem) + dinv + cursor ----
#define SCAN_CH 16
__global__ __launch_bounds__(1024) void k_scan1(const int* __restrict__ cnt,
                                                int* __restrict__ roff,
                                                int* __restrict__ cursor,
                                                float* __restrict__ dinv, int n) {
  __shared__ int sh[1024];
  const int t = threadIdx.x;
  const int base = t * SCAN_CH;
  int vv[SCAN_CH], loc[SCAN_CH];
  int sum = 0;
#pragma unroll
  for (int i = 0; i < SCAN_CH; ++i) {
    int idx = base + i;
    int v = (idx < n) ? cnt[idx] : 0;
    vv[i] = v;
    loc[i] = sum;
    sum += v;
  }
  sh[t] = sum;
  __syncthreads();
  for (int s = 1; s < 1024; s <<= 1) {
    int v = (t >= s) ? sh[t - s] : 0;
    __syncthreads();
    sh[t] += v;
    __syncthreads();
  }
  int tex = sh[t] - sum;
#pragma unroll
  for (int i = 0; i < SCAN_CH; ++i) {
    int idx = base + i;
    if (idx < n) {
      int excl = tex + loc[i];
      roff[idx] = excl;
      cursor[idx] = excl;
      dinv[idx] = rsqrtf((float)(vv[i] + 1));  // +1 self-loop
    }
  }
  if (t == 1023) roff[n] = sh[1023];
}

// ---------------- fused scatter (blocks < SB) + weight convert/transpose ----
__global__ __launch_bounds__(256) void k_scat_wconv(
    const int* __restrict__ eic, int* __restrict__ cursor,
    const float* __restrict__ dinv, int2* __restrict__ csrw, int E, int SB,
    const float* __restrict__ W1, const float* __restrict__ W2,
    ushort_t* __restrict__ h1, ushort_t* __restrict__ l1,
    ushort_t* __restrict__ h2, ushort_t* __restrict__ l2) {
  int b = blockIdx.x;
  if (b < SB) {
    int e = b * 256 + threadIdx.x;
    if (e >= E) return;
    int s = eic[e], d = eic[E + e];
    int slot = atomicAdd(&cursor[d], 1);
    int2 val;
    val.x = s;
    val.y = __float_as_int(dinv[s]);
    csrw[slot] = val;
    return;
  }
  int idx = (b - SB) * 256 + threadIdx.x;
  const int S1 = C_IN * C_HID;
  const int S2 = C_HID * C_OUT;
  if (idx >= S1 + S2) return;
  const float* W; ushort_t *hi, *lo; int K, Nn, li;
  if (idx < S1) { W = W1; hi = h1; lo = l1; K = C_IN; Nn = C_HID; li = idx; }
  else { W = W2; hi = h2; lo = l2; K = C_HID; Nn = C_OUT; li = idx - S1; }
  int k = li / Nn, n = li - k * Nn;
  float v = W[li];
  ushort_t h = f2bf(v);
  hi[(size_t)n * K + k] = h;
  lo[(size_t)n * K + k] = f2bf(v - bf2f(h));
}

// ---------------- gather: 4 nodes/block (1 wave each), unroll-8, no waste ---
// EPI=0: rows fp32 (input x), outputs bf16 split. EPI=1: rows bf16 (hw2),
// output fp32 with bias+relu+dropout.
template <int EPI, typename T>
__global__ __launch_bounds__(256) void k_gather4(const int* __restrict__ roff,
                                                 const int2* __restrict__ csrw,
                                                 const float* __restrict__ dinv,
                                                 const T* __restrict__ x,
                                                 const float* __restrict__ bias,
                                                 void* __restrict__ o1,
                                                 void* __restrict__ o2,
                                                 unsigned dk0, unsigned dk1) {
  const int g = threadIdx.x >> 6;
  const int lane = threadIdx.x & 63;
  const int node = blockIdx.x * 4 + g;
  float dd = dinv[node];
  float4 v = row4(x, node, lane);
  float4 acc = make_float4(dd * v.x, dd * v.y, dd * v.z, dd * v.w);
  int p = roff[node], end = roff[node + 1];
  for (; p + 8 <= end; p += 8) {
    int2 ew[8];
#pragma unroll
    for (int i = 0; i < 8; ++i) ew[i] = csrw[p + i];
#pragma unroll
    for (int i = 0; i < 8; ++i) {
      float w = __int_as_float(ew[i].y);
      float4 a = row4(x, ew[i].x, lane);
      acc.x += w * a.x; acc.y += w * a.y; acc.z += w * a.z; acc.w += w * a.w;
    }
  }
  for (; p < end; ++p) {
    int2 e = csrw[p];
    float w = __int_as_float(e.y);
    float4 a = row4(x, e.x, lane);
    acc.x += w * a.x; acc.y += w * a.y; acc.z += w * a.z; acc.w += w * a.w;
  }
  acc.x *= dd; acc.y *= dd; acc.z *= dd; acc.w *= dd;
  if (EPI) {
    float4 bb = ((const float4*)bias)[lane];
    acc.x = fmaxf(acc.x + bb.x, 0.0f);
    acc.y = fmaxf(acc.y + bb.y, 0.0f);
    acc.z = fmaxf(acc.z + bb.z, 0.0f);
    acc.w = fmaxf(acc.w + bb.w, 0.0f);
    unsigned jb = (unsigned)node * 256u + (unsigned)lane * 4u;
    acc.x *= drop_scale(jb + 0u, dk0, dk1);
    acc.y *= drop_scale(jb + 1u, dk0, dk1);
    acc.z *= drop_scale(jb + 2u, dk0, dk1);
    acc.w *= drop_scale(jb + 3u, dk0, dk1);
    ((float4*)o1)[(size_t)node * 64 + lane] = acc;
  } else {
    ushort_t h0 = f2bf(acc.x), h1 = f2bf(acc.y), h2 = f2bf(acc.z), h3 = f2bf(acc.w);
    ushort4 hv = make_ushort4(h0, h1, h2, h3);
    ushort4 lv = make_ushort4(f2bf(acc.x - bf2f(h0)), f2bf(acc.y - bf2f(h1)),
                              f2bf(acc.z - bf2f(h2)), f2bf(acc.w - bf2f(h3)));
    ((ushort4*)o1)[(size_t)node * 64 + lane] = hv;
    ((ushort4*)o2)[(size_t)node * 64 + lane] = lv;
  }
}

// ---------------- bf16x3 MFMA GEMM (round-5 proven VGPR-prefetch staging) ----
// EPI=1: bias+relu+dropout, write bf16 hi/lo. EPI=0: write bf16 hi only.
template <int EPI>
__global__ __launch_bounds__(256) void k_gemm3(
    const ushort_t* __restrict__ Ahi, const ushort_t* __restrict__ Alo,
    const ushort_t* __restrict__ Bhi, const ushort_t* __restrict__ Blo,
    const float* __restrict__ bias,
    ushort_t* __restrict__ Chi, ushort_t* __restrict__ Clo,
    int M, int N, int K, unsigned dk0, unsigned dk1) {
  __shared__ ushort_t sAh[128 * 32], sAl[128 * 32], sBh[128 * 32], sBl[128 * 32];
  const int t = threadIdx.x;
  const int lane = t & 63, wave = t >> 6;
  const int wm = wave & 1, wn = wave >> 1;
  const int quad = lane >> 4, l16 = lane & 15;
  const int row0 = blockIdx.y * 128, col0 = blockIdx.x * 128;
  const int srow = t >> 2;
  const int skc = (t & 3) * 8;

  floatx4 acc[4][4] = {};

  const int ra0 = min(row0 + srow, M - 1);
  const int ra1 = min(row0 + 64 + srow, M - 1);
  const int rb0 = col0 + srow;
  const int rb1 = col0 + 64 + srow;

  for (int kt = 0; kt < K; kt += 32) {
    const size_t ka = (size_t)kt + skc;
    uint4 vA0h = *(const uint4*)(Ahi + (size_t)ra0 * K + ka);
    uint4 vA1h = *(const uint4*)(Ahi + (size_t)ra1 * K + ka);
    uint4 vA0l = *(const uint4*)(Alo + (size_t)ra0 * K + ka);
    uint4 vA1l = *(const uint4*)(Alo + (size_t)ra1 * K + ka);
    uint4 vB0h = *(const uint4*)(Bhi + (size_t)rb0 * K + ka);
    uint4 vB1h = *(const uint4*)(Bhi + (size_t)rb1 * K + ka);
    uint4 vB0l = *(const uint4*)(Blo + (size_t)rb0 * K + ka);
    uint4 vB1l = *(const uint4*)(Blo + (size_t)rb1 * K + ka);
    __syncthreads();  // prior iteration's LDS reads complete
    *(uint4*)&sAh[srow * 32 + skc] = vA0h;
    *(uint4*)&sAh[(64 + srow) * 32 + skc] = vA1h;
    *(uint4*)&sAl[srow * 32 + skc] = vA0l;
    *(uint4*)&sAl[(64 + srow) * 32 + skc] = vA1l;
    *(uint4*)&sBh[srow * 32 + skc] = vB0h;
    *(uint4*)&sBh[(64 + srow) * 32 + skc] = vB1h;
    *(uint4*)&sBl[srow * 32 + skc] = vB0l;
    *(uint4*)&sBl[(64 + srow) * 32 + skc] = vB1l;
    __syncthreads();

    bf16x8 ah[4], al[4], bh[4], bl[4];
#pragma unroll
    for (int i = 0; i < 4; ++i) {
      int off = (wm * 64 + i * 16 + l16) * 32 + quad * 8;
      ah[i] = *(const bf16x8*)&sAh[off];
      al[i] = *(const bf16x8*)&sAl[off];
    }
#pragma unroll
    for (int j = 0; j < 4; ++j) {
      int off = (wn * 64 + j * 16 + l16) * 32 + quad * 8;
      bh[j] = *(const bf16x8*)&sBh[off];
      bl[j] = *(const bf16x8*)&sBl[off];
    }
#pragma unroll
    for (int i = 0; i < 4; ++i)
#pragma unroll
      for (int j = 0; j < 4; ++j) {
        acc[i][j] = __builtin_amdgcn_mfma_f32_16x16x32_bf16(ah[i], bh[j], acc[i][j], 0, 0, 0);
        acc[i][j] = __builtin_amdgcn_mfma_f32_16x16x32_bf16(ah[i], bl[j], acc[i][j], 0, 0, 0);
        acc[i][j] = __builtin_amdgcn_mfma_f32_16x16x32_bf16(al[i], bh[j], acc[i][j], 0, 0, 0);
      }
  }

#pragma unroll
  for (int i = 0; i < 4; ++i) {
#pragma unroll
    for (int j = 0; j < 4; ++j) {
      int gc = col0 + wn * 64 + j * 16 + l16;
#pragma unroll
      for (int reg = 0; reg < 4; ++reg) {
        int gr = row0 + wm * 64 + i * 16 + quad * 4 + reg;
        if (gr >= M) continue;
        float v = acc[i][j][reg];
        size_t o = (size_t)gr * N + gc;
        if (EPI) {
          v += bias[gc];
          v = fmaxf(v, 0.0f);
          v *= drop_scale((unsigned)gr * (unsigned)N + (unsigned)gc, dk0, dk1);
          ushort_t h = f2bf(v);
          Chi[o] = h;
          Clo[o] = f2bf(v - bf2f(h));
        } else {
          Chi[o] = f2bf(v);  // bf16 hi only (feeds final gather)
        }
      }
    }
  }
}

extern "C" void kernel_launch(void* const* d_in, const int* in_sizes, int n_in,
                              void* d_out, int out_size, void* d_ws, size_t ws_size,
                              hipStream_t stream) {
  const float* x  = (const float*)d_in[0];
  const void*  ei = d_in[1];
  const float* W1 = (const float*)d_in[2];
  const float* b1 = (const float*)d_in[3];
  const float* W2 = (const float*)d_in[4];
  const float* b2 = (const float*)d_in[5];
  float* out = (float*)d_out;

  const int N = in_sizes[0] / C_IN;   // 10000
  const int E = in_sizes[1] / 2;      // 160000
  const int NB = (N + 255) / 256;     // 40

  // foldlike split(key(42)): dk_i = threefry((0,42), (0, i))
  unsigned a0 = 0u, a1 = 0u, b0 = 0u, b1k = 1u;
  tf_rounds(a0, a1, 0u, 42u);   // dk1
  tf_rounds(b0, b1k, 0u, 42u);  // dk2

  // workspace layout
  uintptr_t base = (uintptr_t)d_ws;
  unsigned*  flag   = (unsigned*)base;
  int*       cnt    = (int*)(base + 16 * 1024);               // 40 KB
  int*       roff   = (int*)(base + 64 * 1024);               // 40 KB (+1)
  int*       cursor = (int*)(base + 128 * 1024);              // 40 KB
  float*     dinv   = (float*)(base + 192 * 1024);            // 40 KB
  int*       eic    = (int*)(base + 256 * 1024);              // 1.28 MB
  int2*      csrw   = (int2*)(base + 2u * 1024 * 1024);       // 1.28 MB
  ushort_t*  Ahi    = (ushort_t*)(base + 4u  * 1024 * 1024);  // 5.12 MB
  ushort_t*  Alo    = (ushort_t*)(base + 10u * 1024 * 1024);  // 5.12 MB
  ushort_t*  H1hi   = (ushort_t*)(base + 16u * 1024 * 1024);  // 10.24 MB
  ushort_t*  H1lo   = (ushort_t*)(base + 27u * 1024 * 1024);  // 10.24 MB
  ushort_t*  hw2h   = (ushort_t*)(base + 38u * 1024 * 1024);  // 5.12 MB (bf16)
  ushort_t*  W1thi  = (ushort_t*)(base + 49u * 1024 * 1024);  // 256 KB
  ushort_t*  W1tlo  = (ushort_t*)(base + 49u * 1024 * 1024 + 512 * 1024);
  ushort_t*  W2thi  = (ushort_t*)(base + 50u * 1024 * 1024);
  ushort_t*  W2tlo  = (ushort_t*)(base + 50u * 1024 * 1024 + 512 * 1024);

  dim3 b256(256);
  const int SB = (E + 255) / 256;                             // 625 scatter blocks
  const int WB = (C_IN * C_HID + C_HID * C_OUT + 255) / 256;  // 1024 wconv blocks

  // 1: zero cnt + detect dtype
  k_setup<<<dim3(NB + 1), b256, 0, stream>>>((const unsigned*)ei, flag, 8192, cnt, N, NB);
  // 2: convert edges + degree histogram
  k_convert<<<dim3((2 * E + 255) / 256), b256, 0, stream>>>(ei, flag, eic, cnt, E);
  // 3: scan -> roff/cursor/dinv
  k_scan1<<<dim3(1), dim3(1024), 0, stream>>>(cnt, roff, cursor, dinv, N);
  // 4: scatter into weighted CSR + weight bf16-split transpose
  k_scat_wconv<<<dim3(SB + WB), b256, 0, stream>>>(eic, cursor, dinv, csrw, E, SB,
                                                   W1, W2, W1thi, W1tlo, W2thi, W2tlo);
  // 5: layer-1 aggregate (fp32 rows) -> bf16 split A
  k_gather4<0, float><<<dim3(N / 4), b256, 0, stream>>>(roff, csrw, dinv, x, nullptr,
                                                        Ahi, Alo, 0u, 0u);
  // 6: h1 = drop(relu(agg @ W1 + b1)) -> bf16 split
  k_gemm3<1><<<dim3(C_HID / 128, (N + 127) / 128), b256, 0, stream>>>(
      Ahi, Alo, W1thi, W1tlo, b1, H1hi, H1lo, N, C_HID, C_IN, a0, a1);
  // 7: hw2 = h1 @ W2 -> bf16 hi
  k_gemm3<0><<<dim3(C_OUT / 128, (N + 127) / 128), b256, 0, stream>>>(
      H1hi, H1lo, W2thi, W2tlo, nullptr, hw2h, nullptr, N, C_OUT, C_HID, 0u, 0u);
  // 8: out = drop(relu(A_hat * hw2 + b2))  (bf16 rows)
  k_gather4<1, ushort_t><<<dim3(N / 4), b256, 0, stream>>>(roff, csrw, dinv, hw2h, b2,
                                                           out, nullptr, b0, b1k);
}